// Round 15
// baseline (296.177 us; speedup 1.0000x reference)
//
#include <hip/hip_runtime.h>
#include <math.h>

// MLA decode attention, flash-decoding split + bf16 MFMA core.
// B=64, H=16, latent D=576, V=512, MAX_LEN=4096. fp32 in/out.
//
// R14 vs R13 (138.5us): slim-LDS -> 3 blocks/CU.
//  - V_s deleted (its bytes are K_s's first 512 cols). PV B-frags are
//    assembled from K_s via 8x ds_read_u16 per frag. Since a frag's rows
//    are r = g*8+j (r>>3 == g), an XOR swizzle of the intra-row offset by
//    ((r>>3)<<4) shorts puts the 4 g-groups in disjoint bank-groups ->
//    conflict-free u16 gathers. Swizzle applied identically at stage-write,
//    score b128 reads, and PV u16 reads (granule 16 shorts; preserves b64/
//    b128 alignment; col^swz stays inside the 576-col row).
//  - Stage writes only K (20 b64 + 40 cvtpk/thread, V-transpose deleted).
//  - LDS = K_s 37376 + P_s 5120 = 42496 B -> 3 blocks/CU = 12 waves/CU.
//    Register prefetch dropped (synchronous stage) to fit ~168 VGPR at
//    3 waves/SIMD: cross-block TLP replaces in-block pipelining (R2 lesson;
//    R10's async gained only 13us at 2 blocks).
//  - Kept from R13: log2 softmax w/ skip-rescale + deferred l-reduction,
//    P_s transpose, setprio on MFMA clusters, OOB row clamp, unrolled
//    reduce kernel.

typedef __attribute__((ext_vector_type(8))) short bf16x8;
typedef __attribute__((ext_vector_type(4))) float f32x4;

namespace {
constexpr int NB = 64, NH = 16, MAXLEN = 4096, D = 576, DV = 512;
constexpr int KP = 584;   // K_s row stride (shorts): 1168 B rows, 16B-aligned
constexpr int PP = 40;    // P_s row stride (shorts): 80 B rows, 16B-aligned
constexpr float SCALE_LOG2E = 0.041666666666666664f * 1.4426950408889634f;
constexpr float NEGINF = -1e30f;
}

__device__ __forceinline__ uint32_t cvtpk(float a, float b) {
    uint32_t r;
    asm("v_cvt_pk_bf16_f32 %0, %1, %2" : "=v"(r) : "v"(a), "v"(b));
    return r;   // low16 = bf16(a), high16 = bf16(b)
}

union FragAB { bf16x8 v; uint32_t u[4]; };

__global__ __launch_bounds__(256, 3)
void mla_mfma(const float* __restrict__ qg, const float* __restrict__ kvnew,
              const float* __restrict__ cache, const int* __restrict__ lens,
              float* __restrict__ ws_o, float* __restrict__ ws_ml,
              int nchunk, int chunk)
{
    const int c = blockIdx.x, b = blockIdx.y;
    const int total = lens[b] + 1;
    const int start = c * chunk;
    if (start >= total) return;               // uniform, before any barrier
    const int end = min(start + chunk, total);
    const int newpos = total - 1;

    __shared__ short K_s[32 * KP];            // 37376 B, swizzled bf16
    __shared__ short P_s[4 * 16 * PP];        //  5120 B   (total 42496)

    const int tid  = (int)threadIdx.x;
    const int wave = tid >> 6, lane = tid & 63;
    const int lr = lane & 15, g = lane >> 4;

    const float* vnew = kvnew + (size_t)b * D;
    const float* cb   = cache + (size_t)b * MAXLEN * D;

    const int rg = tid >> 5;                  // staging row-group: rows rg*4+i
    const int cl = tid & 31;                  // staging col-lane

    // ---- Q A-frags: lane holds Q[h=lr][kc*32 + g*8 + j], scale folded ----
    FragAB qf[18];
    {
        const float* qrow = qg + ((size_t)b * NH + lr) * D + g * 8;
        #pragma unroll
        for (int kc = 0; kc < 18; ++kc) {
            float4 x = *(const float4*)(qrow + kc * 32);
            float4 y = *(const float4*)(qrow + kc * 32 + 4);
            qf[kc].u[0] = cvtpk(x.x * SCALE_LOG2E, x.y * SCALE_LOG2E);
            qf[kc].u[1] = cvtpk(x.z * SCALE_LOG2E, x.w * SCALE_LOG2E);
            qf[kc].u[2] = cvtpk(y.x * SCALE_LOG2E, y.y * SCALE_LOG2E);
            qf[kc].u[3] = cvtpk(y.z * SCALE_LOG2E, y.w * SCALE_LOG2E);
        }
    }

    f32x4 acc[8];
    #pragma unroll
    for (int i = 0; i < 8; ++i) acc[i] = (f32x4){0.f, 0.f, 0.f, 0.f};
    float m2[4] = {NEGINF, NEGINF, NEGINF, NEGINF};
    float ll[4] = {0.f, 0.f, 0.f, 0.f};       // lane-local partial sums

    const int swz_st = (rg >> 1) << 4;        // stage swizzle: (row>>3)<<4,
                                              // same for this thread's 4 rows
    const int sw0 = (lr >> 3) << 4;           // score swizzle, rows 0-15
    const int sw1 = ((16 + lr) >> 3) << 4;    // score swizzle, rows 16-31

    for (int r0 = start; r0 < end; r0 += 32) {
        __syncthreads();                      // prev round's K_s reads done

        // ---- stage: 32 rows fp32 -> bf16 K_s (swizzled), synchronous ----
        {
            const int gr0 = r0 + rg * 4;
            const int r0c = min(gr0,     MAXLEN - 1);
            const int r1c = min(gr0 + 1, MAXLEN - 1);
            const int r2c = min(gr0 + 2, MAXLEN - 1);
            const int r3c = min(gr0 + 3, MAXLEN - 1);
            const float* s0 = (gr0     == newpos) ? vnew : (cb + (size_t)r0c * D);
            const float* s1 = (gr0 + 1 == newpos) ? vnew : (cb + (size_t)r1c * D);
            const float* s2 = (gr0 + 2 == newpos) ? vnew : (cb + (size_t)r2c * D);
            const float* s3 = (gr0 + 3 == newpos) ? vnew : (cb + (size_t)r3c * D);
            #pragma unroll
            for (int it = 0; it < 5; ++it) {
                const int cf = 32 * it + cl;
                if (cf < 144) {
                    const int cs = (cf * 4) ^ swz_st;
                    float4 x0 = *(const float4*)(s0 + cf * 4);
                    float4 x1 = *(const float4*)(s1 + cf * 4);
                    float4 x2 = *(const float4*)(s2 + cf * 4);
                    float4 x3 = *(const float4*)(s3 + cf * 4);
                    uint2 w;
                    w.x = cvtpk(x0.x, x0.y); w.y = cvtpk(x0.z, x0.w);
                    *(uint2*)&K_s[(rg * 4 + 0) * KP + cs] = w;
                    w.x = cvtpk(x1.x, x1.y); w.y = cvtpk(x1.z, x1.w);
                    *(uint2*)&K_s[(rg * 4 + 1) * KP + cs] = w;
                    w.x = cvtpk(x2.x, x2.y); w.y = cvtpk(x2.z, x2.w);
                    *(uint2*)&K_s[(rg * 4 + 2) * KP + cs] = w;
                    w.x = cvtpk(x3.x, x3.y); w.y = cvtpk(x3.z, x3.w);
                    *(uint2*)&K_s[(rg * 4 + 3) * KP + cs] = w;
                }
            }
        }
        __syncthreads();                      // stage visible to all waves

        // ---- scores: S[16h, 32r], two 16x16 tiles ----
        f32x4 sc0 = (f32x4){0.f, 0.f, 0.f, 0.f};
        f32x4 sc1 = (f32x4){0.f, 0.f, 0.f, 0.f};
        __builtin_amdgcn_s_setprio(1);
        #pragma unroll
        for (int kc = 0; kc < 18; ++kc) {
            const int col = kc * 32 + g * 8;
            FragAB kb0, kb1;
            kb0.v = *(const bf16x8*)&K_s[lr * KP + (col ^ sw0)];
            kb1.v = *(const bf16x8*)&K_s[(16 + lr) * KP + (col ^ sw1)];
            sc0 = __builtin_amdgcn_mfma_f32_16x16x32_bf16(qf[kc].v, kb0.v, sc0, 0, 0, 0);
            sc1 = __builtin_amdgcn_mfma_f32_16x16x32_bf16(qf[kc].v, kb1.v, sc1, 0, 0, 0);
        }
        __builtin_amdgcn_s_setprio(0);
        // mask invalid rows (lane's D-col = row r0+lr / r0+16+lr)
        if (r0 + lr >= end)      sc0 = (f32x4){NEGINF, NEGINF, NEGINF, NEGINF};
        if (r0 + 16 + lr >= end) sc1 = (f32x4){NEGINF, NEGINF, NEGINF, NEGINF};

        // ---- online softmax (log2 domain), skip-rescale + deferred l ----
        float mt[4];
        int grew = 0;
        #pragma unroll
        for (int i = 0; i < 4; ++i) {
            float t = fmaxf(sc0[i], sc1[i]);
            t = fmaxf(t, __shfl_xor(t, 1));
            t = fmaxf(t, __shfl_xor(t, 2));
            t = fmaxf(t, __shfl_xor(t, 4));
            t = fmaxf(t, __shfl_xor(t, 8));
            mt[i] = t;
            grew |= (t > m2[i]) ? 1 : 0;
        }
        if (__any(grew)) {                    // wave-uniform branch
            float scl[4];
            #pragma unroll
            for (int i = 0; i < 4; ++i) {
                const float nm = fmaxf(m2[i], mt[i]);
                scl[i] = exp2f(m2[i] - nm);
                m2[i] = nm;
                ll[i] *= scl[i];
            }
            const f32x4 scl4 = (f32x4){scl[0], scl[1], scl[2], scl[3]};
            #pragma unroll
            for (int vt = 0; vt < 8; ++vt) acc[vt] = acc[vt] * scl4;
        }
        float p0[4], p1[4];
        #pragma unroll
        for (int i = 0; i < 4; ++i) {
            p0[i] = exp2f(sc0[i] - m2[i]);
            p1[i] = exp2f(sc1[i] - m2[i]);
            ll[i] += p0[i] + p1[i];
        }

        // ---- P -> bf16, per-wave LDS transpose, re-read as PV A-frag ----
        short* pw = &P_s[wave * 16 * PP];
        #pragma unroll
        for (int i = 0; i < 4; ++i) {
            pw[(4 * g + i) * PP + lr]      = (short)cvtpk(p0[i], p0[i]);
            pw[(4 * g + i) * PP + 16 + lr] = (short)cvtpk(p1[i], p1[i]);
        }
        asm volatile("s_waitcnt lgkmcnt(0)" ::: "memory");  // cross-lane RAW
        FragAB pa;
        pa.v = *(const bf16x8*)&pw[lr * PP + g * 8];

        // ---- PV: wave's 128 v-cols; B-frags gathered from K_s (swizzled,
        //      conflict-free: the 4 g-groups hit disjoint bank-groups) ----
        __builtin_amdgcn_s_setprio(1);
        #pragma unroll
        for (int vt = 0; vt < 8; ++vt) {
            const int vcol = (wave * 128 + vt * 16 + lr) ^ (g << 4);
            FragAB vb;
            #pragma unroll
            for (int j2 = 0; j2 < 4; ++j2) {
                union { short s[2]; uint32_t u; } t;
                t.s[0] = K_s[(g * 8 + 2 * j2)     * KP + vcol];
                t.s[1] = K_s[(g * 8 + 2 * j2 + 1) * KP + vcol];
                vb.u[j2] = t.u;
            }
            acc[vt] = __builtin_amdgcn_mfma_f32_16x16x32_bf16(pa.v, vb.v, acc[vt], 0, 0, 0);
        }
        __builtin_amdgcn_s_setprio(0);
    }

    // ---- epilogue: reduce lane-local l across the 16-lane dd-group ----
    #pragma unroll
    for (int i = 0; i < 4; ++i) {
        float s = ll[i];
        s += __shfl_xor(s, 1);
        s += __shfl_xor(s, 2);
        s += __shfl_xor(s, 4);
        s += __shfl_xor(s, 8);
        ll[i] = s;
    }

    // ---- write partials: lane covers h = 4g+i, v = wave*128 + vt*16 + lr --
    float* ob = ws_o + (((size_t)b * nchunk + c) * NH) * DV;
    #pragma unroll
    for (int vt = 0; vt < 8; ++vt) {
        const int v = wave * 128 + vt * 16 + lr;
        #pragma unroll
        for (int i = 0; i < 4; ++i)
            ob[(4 * g + i) * DV + v] = acc[vt][i];
    }
    if (wave == 0 && lr == 0) {
        float* mlb = ws_ml + ((size_t)b * nchunk + c) * NH * 2;
        #pragma unroll
        for (int i = 0; i < 4; ++i) {
            mlb[(4 * g + i) * 2]     = m2[i];   // log2-domain running max
            mlb[(4 * g + i) * 2 + 1] = ll[i];
        }
    }
}

__global__ __launch_bounds__(256)
void mla_reduce(const int* __restrict__ lens,
                const float* __restrict__ ws_o,
                const float* __restrict__ ws_ml,
                float* __restrict__ out,
                int nchunk, int chunk)
{
    const int h = blockIdx.x;
    const int b = blockIdx.y;
    const int tid = (int)threadIdx.x;
    const int total = lens[b] + 1;
    const int nact = min(nchunk, (total + chunk - 1) / chunk);

    float M = NEGINF;
    {
        int c = 0;
        for (; c + 4 <= nact; c += 4) {       // 4 independent loads in flight
            const float m0 = ws_ml[(((size_t)b * nchunk + c    ) * NH + h) * 2];
            const float m1 = ws_ml[(((size_t)b * nchunk + c + 1) * NH + h) * 2];
            const float m2_ = ws_ml[(((size_t)b * nchunk + c + 2) * NH + h) * 2];
            const float m3 = ws_ml[(((size_t)b * nchunk + c + 3) * NH + h) * 2];
            M = fmaxf(M, fmaxf(fmaxf(m0, m1), fmaxf(m2_, m3)));
        }
        for (; c < nact; ++c)
            M = fmaxf(M, ws_ml[(((size_t)b * nchunk + c) * NH + h) * 2]);
    }

    float a0 = 0.f, a1 = 0.f, L = 0.f;
    {
        int c = 0;
        for (; c + 2 <= nact; c += 2) {       // 2 independent iterations
            const size_t mlb0 = (((size_t)b * nchunk + c    ) * NH + h) * 2;
            const size_t mlb1 = (((size_t)b * nchunk + c + 1) * NH + h) * 2;
            const float w0 = exp2f(ws_ml[mlb0] - M);
            const float w1 = exp2f(ws_ml[mlb1] - M);
            const float2 o0 = *(const float2*)&ws_o[
                (((size_t)b * nchunk + c    ) * NH + h) * (size_t)DV + 2 * tid];
            const float2 o1 = *(const float2*)&ws_o[
                (((size_t)b * nchunk + c + 1) * NH + h) * (size_t)DV + 2 * tid];
            L += w0 * ws_ml[mlb0 + 1] + w1 * ws_ml[mlb1 + 1];
            a0 = fmaf(w1, o1.x, fmaf(w0, o0.x, a0));
            a1 = fmaf(w1, o1.y, fmaf(w0, o0.y, a1));
        }
        for (; c < nact; ++c) {
            const size_t mlb = (((size_t)b * nchunk + c) * NH + h) * 2;
            const float w = exp2f(ws_ml[mlb] - M);
            L += w * ws_ml[mlb + 1];
            const float2 o = *(const float2*)&ws_o[
                (((size_t)b * nchunk + c) * NH + h) * (size_t)DV + 2 * tid];
            a0 = fmaf(w, o.x, a0);
            a1 = fmaf(w, o.y, a1);
        }
    }
    const float inv = 1.f / L;
    *(float2*)&out[((size_t)b * NH + h) * (size_t)DV + 2 * tid] =
        make_float2(a0 * inv, a1 * inv);
}

extern "C" void kernel_launch(void* const* d_in, const int* in_sizes, int n_in,
                              void* d_out, int out_size, void* d_ws, size_t ws_size,
                              hipStream_t stream)
{
    (void)in_sizes; (void)n_in; (void)out_size;
    const float* qg    = (const float*)d_in[0];   // [B,H,576]
    const float* kvnew = (const float*)d_in[1];   // [B,1,576]
    const float* cache = (const float*)d_in[2];   // [B,4096,576]
    const int*   lens  = (const int*)d_in[3];     // [B]
    float* out = (float*)d_out;                   // [B,H,512] fp32

    // largest chunk split that fits the workspace (67 MB at nchunk=32)
    int nchunk = 32;
    while (nchunk > 1 &&
           (size_t)NB * nchunk * NH * (DV + 2) * sizeof(float) > ws_size)
        nchunk >>= 1;
    const int chunk = MAXLEN / nchunk;            // multiple of 32

    float* ws_o  = (float*)d_ws;
    float* ws_ml = ws_o + (size_t)NB * nchunk * NH * DV;

    dim3 gA(nchunk, NB);
    mla_mfma<<<gA, 256, 0, stream>>>(qg, kvnew, cache, lens, ws_o, ws_ml,
                                     nchunk, chunk);
    dim3 gB(NH, NB);
    mla_reduce<<<gB, 256, 0, stream>>>(lens, ws_o, ws_ml, out, nchunk, chunk);
}

// Round 16
// 117.799 us; speedup vs baseline: 2.5142x; 2.5142x over previous
//
#include <hip/hip_runtime.h>
#include <math.h>

// MLA decode attention, flash-decoding split + bf16 MFMA core.
// B=64, H=16, latent D=576, V=512, MAX_LEN=4096. fp32 in/out.
//
// R15 = R13 (138.5us, best verified) + nchunk 32->16.
//  - R14's V_s-deletion (PV via 64x ds_read_u16/wave) regressed 2.1x:
//    16 lanes x 2B stride = 4-way bank conflict per read, x64 reads.
//    V must be consumed via wide b64 reads -> dual K_s+Vt layout restored.
//  - nchunk=16 (chunk=256): halves ws_o traffic (67->34 MB each way) and
//    the reduce-kernel loop depth. ~545 active blocks vs 512 residency
//    slots keeps balance acceptable.
//  - R13 kernel body unchanged: half-split register prefetch (A early/
//    B late), dual-write K_s row-major + Vt transposed, 4-wave redundant
//    scores, log2 softmax w/ skip-rescale + deferred l-reduction, P_s
//    transpose, PV 8 mfma/wave, setprio, OOB clamp, LDS 79360B (2 blk/CU).

typedef __attribute__((ext_vector_type(8))) short bf16x8;
typedef __attribute__((ext_vector_type(4))) float f32x4;

namespace {
constexpr int NB = 64, NH = 16, MAXLEN = 4096, D = 576, DV = 512;
constexpr int KP = 584;   // K_s row stride (bf16): 1168 B rows, 16B-aligned
constexpr int VP = 36;    // Vt row stride (bf16): 72 B rows, 8B-aligned
constexpr int PP = 40;    // P_s row stride (bf16)
constexpr float SCALE_LOG2E = 0.041666666666666664f * 1.4426950408889634f;
constexpr float NEGINF = -1e30f;
}

__device__ __forceinline__ uint32_t cvtpk(float a, float b) {
    uint32_t r;
    asm("v_cvt_pk_bf16_f32 %0, %1, %2" : "=v"(r) : "v"(a), "v"(b));
    return r;   // low16 = bf16(a), high16 = bf16(b)
}

union FragAB { bf16x8 v; uint32_t u[4]; };

__global__ __launch_bounds__(256, 2)
void mla_mfma(const float* __restrict__ qg, const float* __restrict__ kvnew,
              const float* __restrict__ cache, const int* __restrict__ lens,
              float* __restrict__ ws_o, float* __restrict__ ws_ml,
              int nchunk, int chunk)
{
    const int c = blockIdx.x, b = blockIdx.y;
    const int total = lens[b] + 1;
    const int start = c * chunk;
    if (start >= total) return;               // uniform, before any barrier
    const int end = min(start + chunk, total);
    const int newpos = total - 1;

    __shared__ short K_s[32 * KP];            // 37376 B row-major bf16
    __shared__ short V_s[DV * VP];            // 36864 B Vt[v][r] bf16
    __shared__ short P_s[4 * 16 * PP];        //  5120 B   (total 79360)

    const int tid  = (int)threadIdx.x;
    const int wave = tid >> 6, lane = tid & 63;
    const int lr = lane & 15, g = lane >> 4;

    const float* vnew = kvnew + (size_t)b * D;
    const float* cb   = cache + (size_t)b * MAXLEN * D;

    const int rg = tid >> 5;                  // staging row-group: rows rg*4+i
    const int cl = tid & 31;                  // staging col-lane

    float4 nxA[2][4];                         // early half (cols f4 0..63)
    float4 nxB[3][4];                         // late half (cols f4 64..143)

#define ROWPTRS(R0N)                                                           \
        const int gr0 = (R0N) + rg * 4;                                        \
        const int r0c = min(gr0,     MAXLEN - 1);                              \
        const int r1c = min(gr0 + 1, MAXLEN - 1);                              \
        const int r2c = min(gr0 + 2, MAXLEN - 1);                              \
        const int r3c = min(gr0 + 3, MAXLEN - 1);                              \
        const float* s0 = (gr0     == newpos) ? vnew : (cb + (size_t)r0c * D); \
        const float* s1 = (gr0 + 1 == newpos) ? vnew : (cb + (size_t)r1c * D); \
        const float* s2 = (gr0 + 2 == newpos) ? vnew : (cb + (size_t)r2c * D); \
        const float* s3 = (gr0 + 3 == newpos) ? vnew : (cb + (size_t)r3c * D);

#define STAGE_LOAD_A(R0N)                                                      \
    {                                                                          \
        ROWPTRS(R0N)                                                           \
        _Pragma("unroll")                                                      \
        for (int it = 0; it < 2; ++it) {                                       \
            const int cf = 32 * it + cl;                                       \
            nxA[it][0] = *(const float4*)(s0 + cf * 4);                        \
            nxA[it][1] = *(const float4*)(s1 + cf * 4);                        \
            nxA[it][2] = *(const float4*)(s2 + cf * 4);                        \
            nxA[it][3] = *(const float4*)(s3 + cf * 4);                        \
        }                                                                      \
    }

#define STAGE_LOAD_B(R0N)                                                      \
    {                                                                          \
        ROWPTRS(R0N)                                                           \
        _Pragma("unroll")                                                      \
        for (int jt = 0; jt < 3; ++jt) {                                       \
            const int cf = 32 * (jt + 2) + cl;                                 \
            if (cf < 144) {                                                    \
                nxB[jt][0] = *(const float4*)(s0 + cf * 4);                    \
                nxB[jt][1] = *(const float4*)(s1 + cf * 4);                    \
                nxB[jt][2] = *(const float4*)(s2 + cf * 4);                    \
                nxB[jt][3] = *(const float4*)(s3 + cf * 4);                    \
            }                                                                  \
        }                                                                      \
    }

#define WRITE_ONE(NX, CF)                                                      \
    {                                                                          \
        uint2 w;                                                               \
        w.x = cvtpk(NX[0].x, NX[0].y); w.y = cvtpk(NX[0].z, NX[0].w);          \
        *(uint2*)&K_s[(rg * 4 + 0) * KP + (CF) * 4] = w;                       \
        w.x = cvtpk(NX[1].x, NX[1].y); w.y = cvtpk(NX[1].z, NX[1].w);          \
        *(uint2*)&K_s[(rg * 4 + 1) * KP + (CF) * 4] = w;                       \
        w.x = cvtpk(NX[2].x, NX[2].y); w.y = cvtpk(NX[2].z, NX[2].w);          \
        *(uint2*)&K_s[(rg * 4 + 2) * KP + (CF) * 4] = w;                       \
        w.x = cvtpk(NX[3].x, NX[3].y); w.y = cvtpk(NX[3].z, NX[3].w);          \
        *(uint2*)&K_s[(rg * 4 + 3) * KP + (CF) * 4] = w;                       \
        if ((CF) < 128) {                                                      \
            const int v0 = (CF) * 4;                                           \
            w.x = cvtpk(NX[0].x, NX[1].x); w.y = cvtpk(NX[2].x, NX[3].x);      \
            *(uint2*)&V_s[(v0 + 0) * VP + rg * 4] = w;                         \
            w.x = cvtpk(NX[0].y, NX[1].y); w.y = cvtpk(NX[2].y, NX[3].y);      \
            *(uint2*)&V_s[(v0 + 1) * VP + rg * 4] = w;                         \
            w.x = cvtpk(NX[0].z, NX[1].z); w.y = cvtpk(NX[2].z, NX[3].z);      \
            *(uint2*)&V_s[(v0 + 2) * VP + rg * 4] = w;                         \
            w.x = cvtpk(NX[0].w, NX[1].w); w.y = cvtpk(NX[2].w, NX[3].w);      \
            *(uint2*)&V_s[(v0 + 3) * VP + rg * 4] = w;                         \
        }                                                                      \
    }

#define STAGE_WRITE_A()                                                        \
    {                                                                          \
        _Pragma("unroll")                                                      \
        for (int it = 0; it < 2; ++it) {                                       \
            const int cf = 32 * it + cl;                                       \
            WRITE_ONE(nxA[it], cf)                                             \
        }                                                                      \
    }

#define STAGE_WRITE_B()                                                        \
    {                                                                          \
        _Pragma("unroll")                                                      \
        for (int jt = 0; jt < 3; ++jt) {                                       \
            const int cf = 32 * (jt + 2) + cl;                                 \
            if (cf < 144) { WRITE_ONE(nxB[jt], cf) }                           \
        }                                                                      \
    }

    // ---- Q A-frags: lane holds Q[h=lr][kc*32 + g*8 + j], scale folded ----
    FragAB qf[18];
    {
        const float* qrow = qg + ((size_t)b * NH + lr) * D + g * 8;
        #pragma unroll
        for (int kc = 0; kc < 18; ++kc) {
            float4 x = *(const float4*)(qrow + kc * 32);
            float4 y = *(const float4*)(qrow + kc * 32 + 4);
            qf[kc].u[0] = cvtpk(x.x * SCALE_LOG2E, x.y * SCALE_LOG2E);
            qf[kc].u[1] = cvtpk(x.z * SCALE_LOG2E, x.w * SCALE_LOG2E);
            qf[kc].u[2] = cvtpk(y.x * SCALE_LOG2E, y.y * SCALE_LOG2E);
            qf[kc].u[3] = cvtpk(y.z * SCALE_LOG2E, y.w * SCALE_LOG2E);
        }
    }

    f32x4 acc[8];
    #pragma unroll
    for (int i = 0; i < 8; ++i) acc[i] = (f32x4){0.f, 0.f, 0.f, 0.f};
    float m2[4] = {NEGINF, NEGINF, NEGINF, NEGINF};
    float ll[4] = {0.f, 0.f, 0.f, 0.f};      // lane-local partial sums

    // ---- prologue: stage tile 0 ----
    STAGE_LOAD_A(start);
    STAGE_LOAD_B(start);
    STAGE_WRITE_A();
    STAGE_WRITE_B();
    __syncthreads();

    for (int r0 = start; r0 < end; r0 += 32) {
        const bool have_next = (r0 + 32 < end);     // block-uniform
        if (have_next) STAGE_LOAD_A(r0 + 32);       // early half in flight

        // ---- scores: S[16h, 32r], two 16x16 tiles ----
        f32x4 sc0 = (f32x4){0.f, 0.f, 0.f, 0.f};
        f32x4 sc1 = (f32x4){0.f, 0.f, 0.f, 0.f};
        __builtin_amdgcn_s_setprio(1);
        #pragma unroll
        for (int kc = 0; kc < 18; ++kc) {
            FragAB kb0, kb1;
            kb0.v = *(const bf16x8*)&K_s[lr * KP + kc * 32 + g * 8];
            kb1.v = *(const bf16x8*)&K_s[(16 + lr) * KP + kc * 32 + g * 8];
            sc0 = __builtin_amdgcn_mfma_f32_16x16x32_bf16(qf[kc].v, kb0.v, sc0, 0, 0, 0);
            sc1 = __builtin_amdgcn_mfma_f32_16x16x32_bf16(qf[kc].v, kb1.v, sc1, 0, 0, 0);
        }
        __builtin_amdgcn_s_setprio(0);
        // mask invalid rows (lane's D-col = row r0+lr / r0+16+lr)
        if (r0 + lr >= end)      sc0 = (f32x4){NEGINF, NEGINF, NEGINF, NEGINF};
        if (r0 + 16 + lr >= end) sc1 = (f32x4){NEGINF, NEGINF, NEGINF, NEGINF};

        // ---- online softmax (log2 domain), skip-rescale + deferred l ----
        float mt[4];
        int grew = 0;
        #pragma unroll
        for (int i = 0; i < 4; ++i) {
            float t = fmaxf(sc0[i], sc1[i]);
            t = fmaxf(t, __shfl_xor(t, 1));
            t = fmaxf(t, __shfl_xor(t, 2));
            t = fmaxf(t, __shfl_xor(t, 4));
            t = fmaxf(t, __shfl_xor(t, 8));
            mt[i] = t;
            grew |= (t > m2[i]) ? 1 : 0;
        }
        if (__any(grew)) {                   // wave-uniform branch
            float scl[4];
            #pragma unroll
            for (int i = 0; i < 4; ++i) {
                const float nm = fmaxf(m2[i], mt[i]);
                scl[i] = exp2f(m2[i] - nm);  // ==1 for non-growing groups
                m2[i] = nm;
                ll[i] *= scl[i];
            }
            const f32x4 scl4 = (f32x4){scl[0], scl[1], scl[2], scl[3]};
            #pragma unroll
            for (int vt = 0; vt < 8; ++vt) acc[vt] = acc[vt] * scl4;
        }
        float p0[4], p1[4];
        #pragma unroll
        for (int i = 0; i < 4; ++i) {
            p0[i] = exp2f(sc0[i] - m2[i]);
            p1[i] = exp2f(sc1[i] - m2[i]);
            ll[i] += p0[i] + p1[i];          // lane-local; reduced at epilogue
        }

        // ---- P -> bf16, per-wave LDS transpose, re-read as PV A-frag ----
        short* pw = &P_s[wave * 16 * PP];
        #pragma unroll
        for (int i = 0; i < 4; ++i) {
            pw[(4 * g + i) * PP + lr]      = (short)cvtpk(p0[i], p0[i]);
            pw[(4 * g + i) * PP + 16 + lr] = (short)cvtpk(p1[i], p1[i]);
        }
        asm volatile("s_waitcnt lgkmcnt(0)" ::: "memory");  // cross-lane RAW
        FragAB pa;
        pa.v = *(const bf16x8*)&pw[lr * PP + g * 8];

        // ---- PV: wave's 128 v-cols, 8 mfma ----
        __builtin_amdgcn_s_setprio(1);
        #pragma unroll
        for (int vt = 0; vt < 8; ++vt) {
            const int v = wave * 128 + vt * 16 + lr;
            FragAB vb;
            *(uint2*)&vb.u[0] = *(const uint2*)&V_s[v * VP + g * 8];
            *(uint2*)&vb.u[2] = *(const uint2*)&V_s[v * VP + g * 8 + 4];
            acc[vt] = __builtin_amdgcn_mfma_f32_16x16x32_bf16(pa.v, vb.v, acc[vt], 0, 0, 0);
        }
        __builtin_amdgcn_s_setprio(0);

        if (have_next) STAGE_LOAD_B(r0 + 32);   // late half issued pre-barrier
        __syncthreads();                        // all waves done reading LDS
        if (have_next) { STAGE_WRITE_A(); STAGE_WRITE_B(); }
        __syncthreads();                        // next round staged
    }

    // ---- epilogue: reduce lane-local l across the 16-lane dd-group ----
    #pragma unroll
    for (int i = 0; i < 4; ++i) {
        float s = ll[i];
        s += __shfl_xor(s, 1);
        s += __shfl_xor(s, 2);
        s += __shfl_xor(s, 4);
        s += __shfl_xor(s, 8);
        ll[i] = s;
    }

    // ---- write partials: lane covers h = 4g+i, v = wave*128 + vt*16 + lr --
    float* ob = ws_o + (((size_t)b * nchunk + c) * NH) * DV;
    #pragma unroll
    for (int vt = 0; vt < 8; ++vt) {
        const int v = wave * 128 + vt * 16 + lr;
        #pragma unroll
        for (int i = 0; i < 4; ++i)
            ob[(4 * g + i) * DV + v] = acc[vt][i];
    }
    if (wave == 0 && lr == 0) {
        float* mlb = ws_ml + ((size_t)b * nchunk + c) * NH * 2;
        #pragma unroll
        for (int i = 0; i < 4; ++i) {
            mlb[(4 * g + i) * 2]     = m2[i];   // log2-domain running max
            mlb[(4 * g + i) * 2 + 1] = ll[i];
        }
    }
#undef STAGE_LOAD_A
#undef STAGE_LOAD_B
#undef STAGE_WRITE_A
#undef STAGE_WRITE_B
#undef WRITE_ONE
#undef ROWPTRS
}

__global__ __launch_bounds__(256)
void mla_reduce(const int* __restrict__ lens,
                const float* __restrict__ ws_o,
                const float* __restrict__ ws_ml,
                float* __restrict__ out,
                int nchunk, int chunk)
{
    const int h = blockIdx.x;
    const int b = blockIdx.y;
    const int tid = (int)threadIdx.x;
    const int total = lens[b] + 1;
    const int nact = min(nchunk, (total + chunk - 1) / chunk);

    float M = NEGINF;
    {
        int c = 0;
        for (; c + 4 <= nact; c += 4) {       // 4 independent loads in flight
            const float m0 = ws_ml[(((size_t)b * nchunk + c    ) * NH + h) * 2];
            const float m1 = ws_ml[(((size_t)b * nchunk + c + 1) * NH + h) * 2];
            const float m2_ = ws_ml[(((size_t)b * nchunk + c + 2) * NH + h) * 2];
            const float m3 = ws_ml[(((size_t)b * nchunk + c + 3) * NH + h) * 2];
            M = fmaxf(M, fmaxf(fmaxf(m0, m1), fmaxf(m2_, m3)));
        }
        for (; c < nact; ++c)
            M = fmaxf(M, ws_ml[(((size_t)b * nchunk + c) * NH + h) * 2]);
    }

    float a0 = 0.f, a1 = 0.f, L = 0.f;
    {
        int c = 0;
        for (; c + 2 <= nact; c += 2) {       // 2 independent iterations
            const size_t mlb0 = (((size_t)b * nchunk + c    ) * NH + h) * 2;
            const size_t mlb1 = (((size_t)b * nchunk + c + 1) * NH + h) * 2;
            const float w0 = exp2f(ws_ml[mlb0] - M);
            const float w1 = exp2f(ws_ml[mlb1] - M);
            const float2 o0 = *(const float2*)&ws_o[
                (((size_t)b * nchunk + c    ) * NH + h) * (size_t)DV + 2 * tid];
            const float2 o1 = *(const float2*)&ws_o[
                (((size_t)b * nchunk + c + 1) * NH + h) * (size_t)DV + 2 * tid];
            L += w0 * ws_ml[mlb0 + 1] + w1 * ws_ml[mlb1 + 1];
            a0 = fmaf(w1, o1.x, fmaf(w0, o0.x, a0));
            a1 = fmaf(w1, o1.y, fmaf(w0, o0.y, a1));
        }
        for (; c < nact; ++c) {
            const size_t mlb = (((size_t)b * nchunk + c) * NH + h) * 2;
            const float w = exp2f(ws_ml[mlb] - M);
            L += w * ws_ml[mlb + 1];
            const float2 o = *(const float2*)&ws_o[
                (((size_t)b * nchunk + c) * NH + h) * (size_t)DV + 2 * tid];
            a0 = fmaf(w, o.x, a0);
            a1 = fmaf(w, o.y, a1);
        }
    }
    const float inv = 1.f / L;
    *(float2*)&out[((size_t)b * NH + h) * (size_t)DV + 2 * tid] =
        make_float2(a0 * inv, a1 * inv);
}

extern "C" void kernel_launch(void* const* d_in, const int* in_sizes, int n_in,
                              void* d_out, int out_size, void* d_ws, size_t ws_size,
                              hipStream_t stream)
{
    (void)in_sizes; (void)n_in; (void)out_size;
    const float* qg    = (const float*)d_in[0];   // [B,H,576]
    const float* kvnew = (const float*)d_in[1];   // [B,1,576]
    const float* cache = (const float*)d_in[2];   // [B,4096,576]
    const int*   lens  = (const int*)d_in[3];     // [B]
    float* out = (float*)d_out;                   // [B,H,512] fp32

    // R15: nchunk=16 (chunk=256) — halves ws traffic + reduce loop depth.
    int nchunk = 16;
    while (nchunk > 1 &&
           (size_t)NB * nchunk * NH * (DV + 2) * sizeof(float) > ws_size)
        nchunk >>= 1;
    const int chunk = MAXLEN / nchunk;            // multiple of 32

    float* ws_o  = (float*)d_ws;
    float* ws_ml = ws_o + (size_t)NB * nchunk * NH * DV;

    dim3 gA(nchunk, NB);
    mla_mfma<<<gA, 256, 0, stream>>>(qg, kvnew, cache, lens, ws_o, ws_ml,
                                     nchunk, chunk);
    dim3 gB(NH, NB);
    mla_reduce<<<gB, 256, 0, stream>>>(lens, ws_o, ws_ml, out, nchunk, chunk);
}